// Round 6
// baseline (28.295 us; speedup 1.0000x reference)
//
#include <hip/hip_runtime.h>
#include <hip/hip_bf16.h>

#define EPS 1e-8f

#define BB 16
#define CC 256
#define TT 512
#define LL 4096
#define KC  32    // t-chunk
#define TCB 128   // c-tile
#define TLB 64    // l-tile
#define XR  40    // LDS row stride in ushorts

typedef __attribute__((ext_vector_type(8))) short short8;
typedef __attribute__((ext_vector_type(4))) float f32x4;

__device__ __forceinline__ unsigned short bfbits(float f) {
    __hip_bfloat16 h = __float2bfloat16(f);
    return *(unsigned short*)&h;
}
__device__ __forceinline__ unsigned int pack2(float lo, float hi) {
    return (unsigned int)bfbits(lo) | ((unsigned int)bfbits(hi) << 16);
}

// ---------------------------------------------------------------------------
// Kernel 1: per-batch cumsum via wave shuffle scan.
// center = cumsum - 0.5*w ; nhis = -0.5/(sg^2+eps) ; delta = band half-width
// ---------------------------------------------------------------------------
__global__ __launch_bounds__(512)
void scan_kernel(const float* __restrict__ w,
                 const float* __restrict__ sigma_scale,
                 float* __restrict__ center,
                 float* __restrict__ nhis,
                 float* __restrict__ delta) {
    const int b = blockIdx.x;
    const int t = threadIdx.x;       // 512
    const int lane = t & 63;
    const int wid  = t >> 6;
    __shared__ float part[8], offs[8], wmx[8];

    const float wv = w[b * TT + t];
    float v = wv;
#pragma unroll
    for (int o = 1; o < 64; o <<= 1) {
        float u = __shfl_up(v, o);
        if (lane >= o) v += u;
    }
    float m = wv;
#pragma unroll
    for (int o = 1; o < 64; o <<= 1) m = fmaxf(m, __shfl_xor(m, o));
    if (lane == 63) part[wid] = v;
    if (lane == 0)  wmx[wid] = m;
    __syncthreads();
    const float ss = sigma_scale[0];
    if (t == 0) {
        float run = 0.0f, mm = 0.0f;
#pragma unroll
        for (int i = 0; i < 8; ++i) {
            offs[i] = run;
            run += part[i];
            mm = fmaxf(mm, wmx[i]);
        }
        delta[b] = 8.0f * (mm * ss + 1e-4f) + 1.0f;
    }
    __syncthreads();
    v += offs[wid];
    center[b * TT + t] = v - 0.5f * wv;
    const float sg = wv * ss;
    nhis[b * TT + t] = -0.5f / (sg * sg + EPS);
}

// ---------------------------------------------------------------------------
// Kernel 2: banded fused GEMM (round-4 known-good pipeline), x_mask folded
// into the weights:  out = x . (diag(xm) . W) ; denominator uses raw exp.
// Block: 128c x 64l, K-band in chunks of 32 t. 256 thr = 4 waves, 32c/wave.
// ---------------------------------------------------------------------------

#define ISSUE(tc_)                                                              \
    {                                                                           \
        _Pragma("unroll")                                                       \
        for (int i = 0; i < 4; ++i) {                                           \
            const int idx4 = tid + 256 * i;                                     \
            const int c    = idx4 >> 3;                                         \
            const int t4   = idx4 & 7;                                          \
            gx[i] = *(const float4*)&x[xbase + (size_t)c * TT + (tc_) + t4 * 4];\
        }                                                                       \
    }

#define WRITEX(buf_)                                                            \
    {                                                                           \
        _Pragma("unroll")                                                       \
        for (int i = 0; i < 4; ++i) {                                           \
            const int idx4 = tid + 256 * i;                                     \
            const int c    = idx4 >> 3;                                         \
            const int t4   = idx4 & 7;                                          \
            ushort4 v4;                                                         \
            v4.x = bfbits(gx[i].x);                                             \
            v4.y = bfbits(gx[i].y);                                             \
            v4.z = bfbits(gx[i].z);                                             \
            v4.w = bfbits(gx[i].w);                                             \
            *(ushort4*)&xs[buf_][c][t4 * 4] = v4;                               \
        }                                                                       \
    }

#define EXPW(tc_, buf_)                                                         \
    {                                                                           \
        _Pragma("unroll")                                                       \
        for (int i = 0; i < 2; ++i) {                                           \
            const int slot  = tid + 256 * i;                                    \
            const int l_loc = slot >> 3;                                        \
            const int t4    = slot & 7;                                         \
            const int t0    = (tc_) + t4 * 4;                                   \
            const float4 cv = *(const float4*)&center[bTT + t0];                \
            const float4 nv = *(const float4*)&nhis[bTT + t0];                  \
            const float4 xm = *(const float4*)&x_mask[bTT + t0];                \
            const float posf = (float)(l0 + l_loc);                             \
            float mu, e0, e1, e2, e3;                                           \
            mu = posf - cv.x; e0 = __expf(mu * mu * nv.x);                      \
            mu = posf - cv.y; e1 = __expf(mu * mu * nv.y);                      \
            mu = posf - cv.z; e2 = __expf(mu * mu * nv.z);                      \
            mu = posf - cv.w; e3 = __expf(mu * mu * nv.w);                      \
            const float ps = (e0 + e1) + (e2 + e3);                             \
            if (i == 0) p0 += ps; else p1 += ps;                                \
            uint2 pk;                                                           \
            pk.x = pack2(e0 * xm.x, e1 * xm.y);                                 \
            pk.y = pack2(e2 * xm.z, e3 * xm.w);                                 \
            *(uint2*)&ws[buf_][l_loc][t4 * 4] = pk;                             \
        }                                                                       \
    }

#define MFMA_STEP(buf_)                                                         \
    {                                                                           \
        short8 af[2], bfr[4];                                                   \
        _Pragma("unroll")                                                       \
        for (int m = 0; m < 2; ++m)                                             \
            af[m] = *(const short8*)&xs[buf_][wv * 32 + m * 16 + lq][lg * 8];   \
        _Pragma("unroll")                                                       \
        for (int n = 0; n < 4; ++n)                                             \
            bfr[n] = *(const short8*)&ws[buf_][n * 16 + lq][lg * 8];            \
        _Pragma("unroll")                                                       \
        for (int m = 0; m < 2; ++m)                                             \
            _Pragma("unroll")                                                   \
            for (int n = 0; n < 4; ++n)                                         \
                acc[m][n] = __builtin_amdgcn_mfma_f32_16x16x32_bf16(            \
                    af[m], bfr[n], acc[m][n], 0, 0, 0);                         \
    }

__global__ __launch_bounds__(256, 4)
void fused_kernel(const float* __restrict__ x,
                  const float* __restrict__ x_mask,
                  const float* __restrict__ y_mask,
                  const float* __restrict__ center,
                  const float* __restrict__ nhis,
                  const float* __restrict__ delta,
                  float* __restrict__ out) {
    __shared__ unsigned short xs[2][TCB][XR];  // 20.0 KB
    __shared__ unsigned short ws[2][TLB][XR];  // 10.0 KB
    __shared__ float dsum[TLB];
    __shared__ float sscale[TLB];
    __shared__ int tmin_s, tmax_s;

    // XCD-chunked swizzle: 2048 blocks, 8 XCDs -> XCD k owns batches 2k,2k+1.
    const int gid = blockIdx.x;
    const int lid = (gid & 7) * 256 + (gid >> 3);
    const int b   = lid >> 7;
    const int rr_ = lid & 127;
    const int l0  = (rr_ >> 1) * TLB;
    const int c0  = (rr_ & 1) * TCB;

    const int tid  = threadIdx.x;
    const int lane = tid & 63;
    const int wv   = tid >> 6;
    const int lq   = lane & 15;
    const int lg   = lane >> 4;
    const int bTT  = b * TT;
    const size_t xbase = (size_t)(b * CC + c0) * TT;

    if (tid == 0) { tmin_s = TT; tmax_s = -1; }
    __syncthreads();
    const float D  = delta[b];
    const float lo = (float)l0 - D;
    const float hi = (float)(l0 + TLB - 1) + D;
#pragma unroll
    for (int i = 0; i < 2; ++i) {
        const int tt = tid + 256 * i;
        const float c = center[bTT + tt];
        if (c >= lo && c <= hi) {
            atomicMin(&tmin_s, tt);
            atomicMax(&tmax_s, tt);
        }
    }
    __syncthreads();
    const int tlo = tmin_s & ~(KC - 1);
    const int nch = (tmax_s >= 0) ? ((((tmax_s & ~(KC - 1)) + KC) - tlo) / KC) : 0;

    f32x4 acc[2][4];
#pragma unroll
    for (int m = 0; m < 2; ++m)
#pragma unroll
        for (int n = 0; n < 4; ++n) acc[m][n] = (f32x4)0.0f;
    float p0 = 0.0f, p1 = 0.0f;

    float4 gx[4];

    if (nch > 0) {
        ISSUE(tlo);
        EXPW(tlo, 0);
        WRITEX(0);
        __syncthreads();
        for (int i = 0; i < nch; ++i) {
            const int cur = i & 1;
            const int tc1 = tlo + (i + 1) * KC;
            if (i + 1 < nch) {
                ISSUE(tc1);
                EXPW(tc1, cur ^ 1);
            }
            MFMA_STEP(cur);
            if (i + 1 < nch) WRITEX(cur ^ 1);
            __syncthreads();
        }
    }

    // ---- denominator: 8 lanes (t-groups) per l; reduce, publish ----
#pragma unroll
    for (int o = 1; o < 8; o <<= 1) {
        p0 += __shfl_xor(p0, o);
        p1 += __shfl_xor(p1, o);
    }
    if ((tid & 7) == 0) {
        dsum[tid >> 3]        = p0;
        dsum[(tid >> 3) + 32] = p1;
    }
    __syncthreads();
    if (tid < TLB)
        sscale[tid] = y_mask[b * LL + l0 + tid] / (dsum[tid] + EPS);
    __syncthreads();

    // ---- epilogue ----
    float sc[4];
#pragma unroll
    for (int n = 0; n < 4; ++n) sc[n] = sscale[n * 16 + lq];

    const size_t obase = (size_t)(b * CC + c0) * LL + l0;
#pragma unroll
    for (int m = 0; m < 2; ++m) {
#pragma unroll
        for (int r = 0; r < 4; ++r) {
            const int c = wv * 32 + m * 16 + lg * 4 + r;
            float* op = &out[obase + (size_t)c * LL];
#pragma unroll
            for (int n = 0; n < 4; ++n)
                op[n * 16 + lq] = acc[m][n][r] * sc[n];
        }
    }
}

extern "C" void kernel_launch(void* const* d_in, const int* in_sizes, int n_in,
                              void* d_out, int out_size, void* d_ws, size_t ws_size,
                              hipStream_t stream) {
    const float* x           = (const float*)d_in[0];
    const float* w           = (const float*)d_in[1];
    const float* x_mask      = (const float*)d_in[2];
    const float* y_mask      = (const float*)d_in[3];
    const float* sigma_scale = (const float*)d_in[4];
    float* out = (float*)d_out;

    float* center = (float*)d_ws;
    float* nhis   = center + BB * TT;
    float* delta  = nhis + BB * TT;

    hipLaunchKernelGGL(scan_kernel, dim3(BB), dim3(512), 0, stream,
                       w, sigma_scale, center, nhis, delta);
    hipLaunchKernelGGL(fused_kernel, dim3((LL / TLB) * (CC / TCB) * BB), dim3(256), 0, stream,
                       x, x_mask, y_mask, center, nhis, delta, out);
}

// Round 7
// 24.285 us; speedup vs baseline: 1.1651x; 1.1651x over previous
//
#include <hip/hip_runtime.h>
#include <hip/hip_bf16.h>

#define EPS 1e-8f

#define BB 16
#define CC 256
#define TT 512
#define LL 4096
#define KC  32    // t-chunk
#define TCB 128   // c-tile
#define TLB 128   // l-tile
#define XR  40    // ws row stride in ushorts (80B, 16B-aligned rows)

typedef __attribute__((ext_vector_type(8))) short short8;
typedef __attribute__((ext_vector_type(4))) float f32x4;

__device__ __forceinline__ unsigned short bfbits(float f) {
    __hip_bfloat16 h = __float2bfloat16(f);
    return *(unsigned short*)&h;
}
__device__ __forceinline__ unsigned int pack2(float lo, float hi) {
    return (unsigned int)bfbits(lo) | ((unsigned int)bfbits(hi) << 16);
}

// ---------------------------------------------------------------------------
// Single fused kernel:
//   phase 0: per-block redundant scan of w[b,:] -> cen/nh/xm in LDS + delta
//   phase 1: band-find [tlo, tlo+nch*KC) via monotone-center range test
//   phase 2: banded GEMM: A-frags straight from global x (L2-hot, no LDS),
//            W chunk = exp(mu^2*nh)*xm in double-buffered LDS (bf16),
//            raw-exp partial sums -> in-kernel denominator
//   phase 3: epilogue scale by y_mask/(den+eps), store fp32
// Block: 128c x 128l, 256 thr = 4 waves (32c each, acc 2x8 of 16x16).
// Grid: 1024 = 4 blocks/CU x 256 CU -> one residency round.
// ---------------------------------------------------------------------------

#define EXPW(tc_, buf_)                                                         \
    {                                                                           \
        _Pragma("unroll")                                                       \
        for (int i_ = 0; i_ < 2; ++i_) {                                        \
            const int slot  = tid + 256 * i_;                                   \
            const int l_loc = slot >> 2;                                        \
            const int tg    = slot & 3;                                         \
            const int t0    = (tc_) + tg * 8;                                   \
            const float4 cv0 = *(const float4*)&cen_s[t0];                      \
            const float4 cv1 = *(const float4*)&cen_s[t0 + 4];                  \
            const float4 nv0 = *(const float4*)&nh_s[t0];                       \
            const float4 nv1 = *(const float4*)&nh_s[t0 + 4];                   \
            const float4 xk0 = *(const float4*)&xm_s[t0];                       \
            const float4 xk1 = *(const float4*)&xm_s[t0 + 4];                   \
            const float posf = (float)(l0 + l_loc);                             \
            float mu, e0, e1, e2, e3, e4, e5, e6, e7;                           \
            mu = posf - cv0.x; e0 = __expf(mu * mu * nv0.x);                    \
            mu = posf - cv0.y; e1 = __expf(mu * mu * nv0.y);                    \
            mu = posf - cv0.z; e2 = __expf(mu * mu * nv0.z);                    \
            mu = posf - cv0.w; e3 = __expf(mu * mu * nv0.w);                    \
            mu = posf - cv1.x; e4 = __expf(mu * mu * nv1.x);                    \
            mu = posf - cv1.y; e5 = __expf(mu * mu * nv1.y);                    \
            mu = posf - cv1.z; e6 = __expf(mu * mu * nv1.z);                    \
            mu = posf - cv1.w; e7 = __expf(mu * mu * nv1.w);                    \
            const float ps = ((e0 + e1) + (e2 + e3)) + ((e4 + e5) + (e6 + e7)); \
            if (i_ == 0) p0 += ps; else p1 += ps;                               \
            uint4 pk;                                                           \
            pk.x = pack2(e0 * xk0.x, e1 * xk0.y);                               \
            pk.y = pack2(e2 * xk0.z, e3 * xk0.w);                               \
            pk.z = pack2(e4 * xk1.x, e5 * xk1.y);                               \
            pk.w = pack2(e6 * xk1.z, e7 * xk1.w);                               \
            *(uint4*)&ws[buf_][l_loc][tg * 8] = pk;                             \
        }                                                                       \
    }

#define AFRAG(AF, crow_, tc_)                                                   \
    {                                                                           \
        const float* xp = &x[xbase + (size_t)(crow_) * TT + (tc_) + lg * 8];    \
        const float4 a0 = *(const float4*)xp;                                   \
        const float4 a1 = *(const float4*)(xp + 4);                             \
        uint4 ap;                                                               \
        ap.x = pack2(a0.x, a0.y);                                               \
        ap.y = pack2(a0.z, a0.w);                                               \
        ap.z = pack2(a1.x, a1.y);                                               \
        ap.w = pack2(a1.z, a1.w);                                               \
        AF = *(short8*)&ap;                                                     \
    }

#define MFMA_STEP(buf_, tc_)                                                    \
    {                                                                           \
        short8 af0, af1;                                                        \
        AFRAG(af0, wv * 32 + lq, tc_);                                          \
        AFRAG(af1, wv * 32 + 16 + lq, tc_);                                     \
        _Pragma("unroll")                                                       \
        for (int n = 0; n < 8; ++n) {                                           \
            const short8 bfr = *(const short8*)&ws[buf_][n * 16 + lq][lg * 8];  \
            acc0[n] = __builtin_amdgcn_mfma_f32_16x16x32_bf16(af0, bfr, acc0[n], 0, 0, 0); \
            acc1[n] = __builtin_amdgcn_mfma_f32_16x16x32_bf16(af1, bfr, acc1[n], 0, 0, 0); \
        }                                                                       \
    }

__global__ __launch_bounds__(256, 4)
void fused_kernel(const float* __restrict__ x,
                  const float* __restrict__ w,
                  const float* __restrict__ x_mask,
                  const float* __restrict__ y_mask,
                  const float* __restrict__ sigma_scale,
                  float* __restrict__ out) {
    __shared__ unsigned short ws[2][TLB][XR];  // 20.0 KB
    __shared__ float cen_s[TT], nh_s[TT], xm_s[TT];  // 6 KB
    __shared__ float dsum[TLB], sscale[TLB];
    __shared__ float part[4], wmx[4], offs[4];
    __shared__ float sdelta;
    __shared__ int tmin_s, tmax_s;

    // XCD-chunked bijective swizzle: 1024 blocks, XCD k -> batches 2k,2k+1.
    const int gid = blockIdx.x;
    const int lid = (gid & 7) * 128 + (gid >> 3);
    const int b   = lid >> 6;
    const int rr  = lid & 63;
    const int l0  = (rr >> 1) * TLB;
    const int c0  = (rr & 1) * TCB;

    const int tid  = threadIdx.x;
    const int lane = tid & 63;
    const int wid  = tid >> 6;   // wave id == c-subtile
    const int wv   = wid;
    const int lq   = lane & 15;
    const int lg   = lane >> 4;
    const int bTT  = b * TT;
    const size_t xbase = (size_t)(b * CC + c0) * TT;

    if (tid == 0) { tmin_s = TT; tmax_s = -1; }

    // ---- phase 0: fused scan (2 w elems per thread) ----
    const int t2 = tid * 2;
    const float2 w2  = *(const float2*)&w[bTT + t2];
    const float2 xm2 = *(const float2*)&x_mask[bTT + t2];
    const float ss = sigma_scale[0];
    const float pairsum = w2.x + w2.y;
    float v = pairsum;
#pragma unroll
    for (int o = 1; o < 64; o <<= 1) {
        float u = __shfl_up(v, o);
        if (lane >= o) v += u;
    }
    float pm = fmaxf(w2.x, w2.y);
#pragma unroll
    for (int o = 1; o < 64; o <<= 1) pm = fmaxf(pm, __shfl_xor(pm, o));
    if (lane == 63) part[wid] = v;
    if (lane == 0)  wmx[wid] = pm;
    __syncthreads();
    if (tid == 0) {
        float run = 0.0f, mm = 0.0f;
#pragma unroll
        for (int i = 0; i < 4; ++i) {
            offs[i] = run;
            run += part[i];
            mm = fmaxf(mm, wmx[i]);
        }
        // cutoff |mu| > 8*sigma_eff: excluded exp <= e^-32 ~ 1.3e-14 << eps
        sdelta = 8.0f * (mm * ss + 1e-4f) + 1.0f;
    }
    __syncthreads();
    const float base = offs[wid] + v - pairsum;   // exclusive prefix
    const float cum1 = base + w2.x;
    const float cum2 = cum1 + w2.y;
    const float cenA = cum1 - 0.5f * w2.x;
    const float cenB = cum2 - 0.5f * w2.y;
    cen_s[t2]     = cenA;
    cen_s[t2 + 1] = cenB;
    const float sgA = w2.x * ss, sgB = w2.y * ss;
    nh_s[t2]     = -0.5f / (sgA * sgA + EPS);
    nh_s[t2 + 1] = -0.5f / (sgB * sgB + EPS);
    xm_s[t2]     = xm2.x;
    xm_s[t2 + 1] = xm2.y;

    // ---- phase 1: band-find ----
    const float D  = sdelta;
    const float lo = (float)l0 - D;
    const float hi = (float)(l0 + TLB - 1) + D;
    if (cenA >= lo && cenA <= hi) { atomicMin(&tmin_s, t2);     atomicMax(&tmax_s, t2); }
    if (cenB >= lo && cenB <= hi) { atomicMin(&tmin_s, t2 + 1); atomicMax(&tmax_s, t2 + 1); }
    __syncthreads();   // cen/nh/xm LDS + tmin/tmax ready
    const int tlo = tmin_s & ~(KC - 1);
    const int nch = (tmax_s >= 0) ? ((((tmax_s & ~(KC - 1)) + KC) - tlo) / KC) : 0;

    f32x4 acc0[8], acc1[8];
#pragma unroll
    for (int n = 0; n < 8; ++n) { acc0[n] = (f32x4)0.0f; acc1[n] = (f32x4)0.0f; }
    float p0 = 0.0f, p1 = 0.0f;

    // ---- phase 2: banded pipelined GEMM ----
    if (nch > 0) {
        EXPW(tlo, 0);
        __syncthreads();
        for (int i = 0; i < nch; ++i) {
            const int cur = i & 1;
            if (i + 1 < nch) EXPW(tlo + (i + 1) * KC, cur ^ 1);
            MFMA_STEP(cur, tlo + i * KC);
            __syncthreads();
        }
    }

    // ---- denominator: 4-lane groups share one l ----
    p0 += __shfl_xor(p0, 1); p0 += __shfl_xor(p0, 2);
    p1 += __shfl_xor(p1, 1); p1 += __shfl_xor(p1, 2);
    if ((tid & 3) == 0) {
        dsum[tid >> 2]        = p0;
        dsum[(tid >> 2) + 64] = p1;
    }
    __syncthreads();
    if (tid < TLB)
        sscale[tid] = y_mask[b * LL + l0 + tid] / (dsum[tid] + EPS);
    __syncthreads();

    // ---- phase 3: epilogue ----
    float sc[8];
#pragma unroll
    for (int n = 0; n < 8; ++n) sc[n] = sscale[n * 16 + lq];

    const size_t obase = (size_t)(b * CC + c0) * LL + l0;
#pragma unroll
    for (int r = 0; r < 4; ++r) {
        const int cA = wv * 32 + lg * 4 + r;
        float* opA = &out[obase + (size_t)cA * LL];
#pragma unroll
        for (int n = 0; n < 8; ++n) opA[n * 16 + lq] = acc0[n][r] * sc[n];
        float* opB = opA + 16 * LL;
#pragma unroll
        for (int n = 0; n < 8; ++n) opB[n * 16 + lq] = acc1[n][r] * sc[n];
    }
}

extern "C" void kernel_launch(void* const* d_in, const int* in_sizes, int n_in,
                              void* d_out, int out_size, void* d_ws, size_t ws_size,
                              hipStream_t stream) {
    const float* x           = (const float*)d_in[0];
    const float* w           = (const float*)d_in[1];
    const float* x_mask      = (const float*)d_in[2];
    const float* y_mask      = (const float*)d_in[3];
    const float* sigma_scale = (const float*)d_in[4];
    float* out = (float*)d_out;

    hipLaunchKernelGGL(fused_kernel, dim3((LL / TLB) * (CC / TCB) * BB), dim3(256), 0, stream,
                       x, w, x_mask, y_mask, sigma_scale, out);
}